// Round 6
// baseline (325.192 us; speedup 1.0000x reference)
//
#include <hip/hip_runtime.h>

#define BINS 10

// R10: decouple load-issue from consumption. Evidence trail: the ~114us floor
// is invariant to compute scheme (ballot 114, LDS-RMW 126), HBM-vs-L3
// residency (R8), and occupancy (R8) — effective delivery 2.35 TB/s vs
// 6.3 TB/s copy ceiling. Diagnosis: burst-load -> drain -> compute phasing
// leaves zero loads in flight ~60% of the time (convoyed waves -> memory
// system idles). Fix: register double-buffer — compute chunk A from regs
// while chunk B's 4 dwordx4 are in flight; every wave keeps ~4KB outstanding
// continuously. Inner loop: R4's register cndmask sums (proven) + R9's
// packed-u64 counts (proven, kills 20 SALU/elem + cross-pipe hazards).
// Per-thread element order unchanged -> bit-identical result.
// __launch_bounds__(256,6): double-buffer needs ~70 VGPR; (256,8) would cap
// at 64 and spill. R8 proved extra occupancy buys nothing here.

__device__ __forceinline__ void elem(float p, float t,
                                     float* __restrict__ sb,
                                     unsigned long long* __restrict__ pk)
{
    float g  = fabsf(p - t);
    float l2 = __log2f(1.0f - g);     // bce = -ln2*log2(1-g); fold -ln2 at end
    int   bi = (int)(g * 10.0f);      // g in (0.01,0.99): bi in [0,9]
    *pk += 1ull << (6 * bi);          // packed 6-bit count (exact, flushed <63)
#pragma unroll
    for (int b = 0; b < BINS; ++b)
        sb[b] += (bi == b) ? l2 : 0.0f;   // v_cmp + cndmask + add, no SALU
}

__device__ __forceinline__ void proc4v(const float4 p, const float4 t,
                                       float* __restrict__ sb,
                                       unsigned long long* __restrict__ pk)
{
    elem(p.x, t.x, sb, pk); elem(p.y, t.y, sb, pk);
    elem(p.z, t.z, sb, pk); elem(p.w, t.w, sb, pk);
}

__device__ __forceinline__ void flushpk(unsigned long long* __restrict__ pk,
                                        unsigned int* __restrict__ cw)
{
#pragma unroll
    for (int b = 0; b < BINS; ++b)
        cw[b] += (unsigned int)((*pk >> (6 * b)) & 63ull);
    *pk = 0ull;
}

__global__ __launch_bounds__(256, 6) void ghm_partial(
    const float4* __restrict__ p4,
    const float4* __restrict__ t4,
    float* __restrict__ gsum,          // [BINS] floats in d_ws
    unsigned int* __restrict__ gcnt,   // [BINS] uints in d_ws
    int n4)
{
    float        sb[BINS];
    unsigned int cw[BINS];
    unsigned long long pk = 0ull;
#pragma unroll
    for (int b = 0; b < BINS; ++b) { sb[b] = 0.0f; cw[b] = 0u; }

    const int tid    = threadIdx.x;
    const int start  = blockIdx.x * blockDim.x + tid;
    const int stride = gridDim.x * blockDim.x;
    const int nch    = n4 / (2 * stride);   // chunks of 2 float4-pairs; 8 here

    int i = start;
    float4 PA0, TA0, PA1, TA1;   // buffer A (named regs: no runtime indexing)
    float4 PB0, TB0, PB1, TB1;   // buffer B

    if (nch > 0) {
        // prologue: fill A with chunk 0
        PA0 = p4[i];          TA0 = t4[i];
        PA1 = p4[i + stride]; TA1 = t4[i + stride];
        i += 2 * stride;
        // steady state: two chunks per outer iteration (A then B), loads for
        // the next chunk issued BEFORE computing the current one.
        for (int c = 0; c + 2 <= nch; c += 2) {
            PB0 = p4[i];          TB0 = t4[i];          // chunk c+1 -> B
            PB1 = p4[i + stride]; TB1 = t4[i + stride];
            i += 2 * stride;
            __builtin_amdgcn_sched_barrier(0);  // B-loads stay above A-compute
            proc4v(PA0, TA0, sb, &pk);
            proc4v(PA1, TA1, sb, &pk);
            if (c + 2 < nch) {                          // chunk c+2 -> A
                PA0 = p4[i];          TA0 = t4[i];
                PA1 = p4[i + stride]; TA1 = t4[i + stride];
                i += 2 * stride;
            }
            __builtin_amdgcn_sched_barrier(0);  // A-loads stay above B-compute
            proc4v(PB0, TB0, sb, &pk);
            proc4v(PB1, TB1, sb, &pk);
            if (c & 2) flushpk(&pk, cw);   // every 32 elems (6-bit cap 63)
        }
        if (nch & 1) {   // odd chunk count: last chunk sits in A
            proc4v(PA0, TA0, sb, &pk);
            proc4v(PA1, TA1, sb, &pk);
        }
        flushpk(&pk, cw);
    }
    // tail: any remaining float4s (n4 not divisible by 2*stride)
    for (int j = start + nch * 2 * stride; j < n4; j += stride) {
        float4 p = p4[j], t = t4[j];
        proc4v(p, t, sb, &pk);
        flushpk(&pk, cw);
    }

    // -------- epilogue: wave reduce -> LDS -> one global atomic/bin/block ----
    __shared__ float        redS[BINS];
    __shared__ unsigned int redC[BINS];
    if (tid < BINS) { redS[tid] = 0.0f; redC[tid] = 0u; }
    __syncthreads();

    const int lane = tid & 63;
#pragma unroll
    for (int b = 0; b < BINS; ++b) {
        float        s = sb[b];
        unsigned int c = cw[b];
#pragma unroll
        for (int off = 32; off > 0; off >>= 1) {
            s += __shfl_down(s, off);
            c += __shfl_down(c, off);
        }
        if (lane == 0) {
            atomicAdd(&redS[b], s);
            atomicAdd(&redC[b], c);
        }
    }
    __syncthreads();
    if (tid < BINS) {
        atomicAdd(&gsum[tid], redS[tid]);
        atomicAdd(&gcnt[tid], redC[tid]);
    }
}

__global__ void ghm_finalize(const float* __restrict__ gsum,
                             const unsigned int* __restrict__ gcnt,
                             float* __restrict__ out)
{
    if (threadIdx.x == 0 && blockIdx.x == 0) {
        int n = 0;
#pragma unroll
        for (int b = 0; b < BINS; ++b) n += (gcnt[b] > 0u) ? 1 : 0;
        float nn = (float)(n > 0 ? n : 1);
        float acc = 0.0f;
#pragma unroll
        for (int b = 0; b < BINS; ++b) {
            if (gcnt[b] > 0u)
                acc += gsum[b] / ((float)gcnt[b] * nn);  // counts < 2^24: exact
        }
        out[0] = -0.6931471805599453f * acc;   // fold -ln(2) from log2 domain
    }
}

extern "C" void kernel_launch(void* const* d_in, const int* in_sizes, int n_in,
                              void* d_out, int out_size, void* d_ws, size_t ws_size,
                              hipStream_t stream)
{
    const float* p = (const float*)d_in[0];   // inputs (probabilities)
    const float* t = (const float*)d_in[1];   // targets (0/1 floats)
    const int n  = in_sizes[0];               // 262144*128
    const int n4 = n >> 2;                    // divisible by 4

    float*        gsum = (float*)d_ws;
    unsigned int* gcnt = (unsigned int*)((char*)d_ws + BINS * sizeof(float));

    // d_ws is re-poisoned to 0xAA before every timed launch — zero it (capturable)
    hipMemsetAsync(d_ws, 0, BINS * (sizeof(float) + sizeof(unsigned int)), stream);

    const int threads = 256;
    const int blocks  = 2048;   // 16 float4/thread -> 8 double-buffered chunks
    ghm_partial<<<blocks, threads, 0, stream>>>(
        (const float4*)p, (const float4*)t, gsum, gcnt, n4);

    ghm_finalize<<<1, 64, 0, stream>>>(gsum, gcnt, (float*)d_out);
}

// Round 7
// 287.861 us; speedup vs baseline: 1.1297x; 1.1297x over previous
//
#include <hip/hip_runtime.h>

#define BINS 10

// R11: R10's double-buffer experiment, uncorrupted. R10 regressed because
// __launch_bounds__(256,6) caps VGPR at ~84 while the pipeline needs ~95:
// the allocator spilled the load buffers to scratch (WRITE_SIZE 0.26KB ->
// 197MB, FETCH +81MB). Silver lining: R10 sustained 2.85 TB/s HBM traffic —
// proof the memory system outruns the baseline's 2.35 TB/s effective rate
// when enough requests are outstanding, supporting the starvation theory.
// Single change vs R10: __launch_bounds__(256,4) -> 128-VGPR cap, no spill.
// (R8 proved occupancy >16 waves/CU is worthless here, so 4 blocks/CU is free.)
// Inner loop: register cndmask sums + packed-u64 counts (both proven exact).
// Per-thread element order unchanged -> bit-identical result.

__device__ __forceinline__ void elem(float p, float t,
                                     float* __restrict__ sb,
                                     unsigned long long* __restrict__ pk)
{
    float g  = fabsf(p - t);
    float l2 = __log2f(1.0f - g);     // bce = -ln2*log2(1-g); fold -ln2 at end
    int   bi = (int)(g * 10.0f);      // g in (0.01,0.99): bi in [0,9]
    *pk += 1ull << (6 * bi);          // packed 6-bit count (exact, flushed <63)
#pragma unroll
    for (int b = 0; b < BINS; ++b)
        sb[b] += (bi == b) ? l2 : 0.0f;   // v_cmp + cndmask + add, no SALU
}

__device__ __forceinline__ void proc4v(const float4 p, const float4 t,
                                       float* __restrict__ sb,
                                       unsigned long long* __restrict__ pk)
{
    elem(p.x, t.x, sb, pk); elem(p.y, t.y, sb, pk);
    elem(p.z, t.z, sb, pk); elem(p.w, t.w, sb, pk);
}

__device__ __forceinline__ void flushpk(unsigned long long* __restrict__ pk,
                                        unsigned int* __restrict__ cw)
{
#pragma unroll
    for (int b = 0; b < BINS; ++b)
        cw[b] += (unsigned int)((*pk >> (6 * b)) & 63ull);
    *pk = 0ull;
}

__global__ __launch_bounds__(256, 4) void ghm_partial(
    const float4* __restrict__ p4,
    const float4* __restrict__ t4,
    float* __restrict__ gsum,          // [BINS] floats in d_ws
    unsigned int* __restrict__ gcnt,   // [BINS] uints in d_ws
    int n4)
{
    float        sb[BINS];
    unsigned int cw[BINS];
    unsigned long long pk = 0ull;
#pragma unroll
    for (int b = 0; b < BINS; ++b) { sb[b] = 0.0f; cw[b] = 0u; }

    const int tid    = threadIdx.x;
    const int start  = blockIdx.x * blockDim.x + tid;
    const int stride = gridDim.x * blockDim.x;
    const int nch    = n4 / (2 * stride);   // chunks of 2 float4-pairs; 8 here

    int i = start;
    float4 PA0, TA0, PA1, TA1;   // buffer A (named regs: no runtime indexing)
    float4 PB0, TB0, PB1, TB1;   // buffer B

    if (nch > 0) {
        // prologue: fill A with chunk 0
        PA0 = p4[i];          TA0 = t4[i];
        PA1 = p4[i + stride]; TA1 = t4[i + stride];
        i += 2 * stride;
        // steady state: two chunks per outer iteration (A then B), loads for
        // the next chunk issued BEFORE computing the current one.
        for (int c = 0; c + 2 <= nch; c += 2) {
            PB0 = p4[i];          TB0 = t4[i];          // chunk c+1 -> B
            PB1 = p4[i + stride]; TB1 = t4[i + stride];
            i += 2 * stride;
            __builtin_amdgcn_sched_barrier(0);  // B-loads stay above A-compute
            proc4v(PA0, TA0, sb, &pk);
            proc4v(PA1, TA1, sb, &pk);
            if (c + 2 < nch) {                          // chunk c+2 -> A
                PA0 = p4[i];          TA0 = t4[i];
                PA1 = p4[i + stride]; TA1 = t4[i + stride];
                i += 2 * stride;
            }
            __builtin_amdgcn_sched_barrier(0);  // A-loads stay above B-compute
            proc4v(PB0, TB0, sb, &pk);
            proc4v(PB1, TB1, sb, &pk);
            if (c & 2) flushpk(&pk, cw);   // every 32 elems (6-bit cap 63)
        }
        if (nch & 1) {   // odd chunk count: last chunk sits in A
            proc4v(PA0, TA0, sb, &pk);
            proc4v(PA1, TA1, sb, &pk);
        }
        flushpk(&pk, cw);
    }
    // tail: any remaining float4s (n4 not divisible by 2*stride)
    for (int j = start + nch * 2 * stride; j < n4; j += stride) {
        float4 p = p4[j], t = t4[j];
        proc4v(p, t, sb, &pk);
        flushpk(&pk, cw);
    }

    // -------- epilogue: wave reduce -> LDS -> one global atomic/bin/block ----
    __shared__ float        redS[BINS];
    __shared__ unsigned int redC[BINS];
    if (tid < BINS) { redS[tid] = 0.0f; redC[tid] = 0u; }
    __syncthreads();

    const int lane = tid & 63;
#pragma unroll
    for (int b = 0; b < BINS; ++b) {
        float        s = sb[b];
        unsigned int c = cw[b];
#pragma unroll
        for (int off = 32; off > 0; off >>= 1) {
            s += __shfl_down(s, off);
            c += __shfl_down(c, off);
        }
        if (lane == 0) {
            atomicAdd(&redS[b], s);
            atomicAdd(&redC[b], c);
        }
    }
    __syncthreads();
    if (tid < BINS) {
        atomicAdd(&gsum[tid], redS[tid]);
        atomicAdd(&gcnt[tid], redC[tid]);
    }
}

__global__ void ghm_finalize(const float* __restrict__ gsum,
                             const unsigned int* __restrict__ gcnt,
                             float* __restrict__ out)
{
    if (threadIdx.x == 0 && blockIdx.x == 0) {
        int n = 0;
#pragma unroll
        for (int b = 0; b < BINS; ++b) n += (gcnt[b] > 0u) ? 1 : 0;
        float nn = (float)(n > 0 ? n : 1);
        float acc = 0.0f;
#pragma unroll
        for (int b = 0; b < BINS; ++b) {
            if (gcnt[b] > 0u)
                acc += gsum[b] / ((float)gcnt[b] * nn);  // counts < 2^24: exact
        }
        out[0] = -0.6931471805599453f * acc;   // fold -ln(2) from log2 domain
    }
}

extern "C" void kernel_launch(void* const* d_in, const int* in_sizes, int n_in,
                              void* d_out, int out_size, void* d_ws, size_t ws_size,
                              hipStream_t stream)
{
    const float* p = (const float*)d_in[0];   // inputs (probabilities)
    const float* t = (const float*)d_in[1];   // targets (0/1 floats)
    const int n  = in_sizes[0];               // 262144*128
    const int n4 = n >> 2;                    // divisible by 4

    float*        gsum = (float*)d_ws;
    unsigned int* gcnt = (unsigned int*)((char*)d_ws + BINS * sizeof(float));

    // d_ws is re-poisoned to 0xAA before every timed launch — zero it (capturable)
    hipMemsetAsync(d_ws, 0, BINS * (sizeof(float) + sizeof(unsigned int)), stream);

    const int threads = 256;
    const int blocks  = 2048;   // 16 float4/thread -> 8 double-buffered chunks
    ghm_partial<<<blocks, threads, 0, stream>>>(
        (const float4*)p, (const float4*)t, gsum, gcnt, n4);

    ghm_finalize<<<1, 64, 0, stream>>>(gsum, gcnt, (float*)d_out);
}